// Round 1
// baseline (680.763 us; speedup 1.0000x reference)
//
#include <hip/hip_runtime.h>
#include <math.h>

// Problem constants (from reference setup_inputs)
constexpr int B    = 64;
constexpr int IC   = 32;
constexpr int PC   = 128;
constexpr int RC   = 32;
constexpr int OUTC = 128;
constexpr int H    = 96;
constexpr int IW   = 320;
constexpr int NPT  = 2048;
constexpr float EPS = 1e-5f;

constexpr int BDIM = 256;
constexpr int NT   = 64;   // points per block

__device__ __forceinline__ float fast_tanh(float v) {
    // tanh(v) = 1 - 2/(exp(2v)+1); safe at +/-inf
    float e = __expf(2.f * v);
    return 1.f - 2.f / (e + 1.f);
}
__device__ __forceinline__ float fast_sigmoid(float v) {
    return 1.f / (1.f + __expf(-v));
}

__global__ __launch_bounds__(BDIM, 2) void rcnn_fused(
    const float* __restrict__ img_map, const float* __restrict__ xy,
    const float* __restrict__ point_feas,
    const float* __restrict__ Wia, const float* __restrict__ b_ia,
    const float* __restrict__ g1, const float* __restrict__ bt1,
    const float* __restrict__ m1, const float* __restrict__ v1,
    const float* __restrict__ Wf1, const float* __restrict__ bf1,
    const float* __restrict__ Wf2, const float* __restrict__ bf2,
    const float* __restrict__ Wf3, const float* __restrict__ bf3,
    const float* __restrict__ Wfuse, const float* __restrict__ b_fuse,
    const float* __restrict__ g2, const float* __restrict__ bt2,
    const float* __restrict__ m2, const float* __restrict__ v2,
    float* __restrict__ out)
{
    __shared__ float s_if[NT][IC + 1];      // img_feas [point][channel], pad -> conflict-free
    __shared__ float s_Ximg[PC][NT];        // img_new rows (X channels 128..255)
    __shared__ float s_Xpf[32][NT];         // point_feas chunk (X channels cb..cb+31)
    __shared__ float s_Wt[32][OUTC + 4];    // W_fuse^T chunk [c][o], pad 4
    __shared__ float s_attp[4][NT];         // attention partial sums
    // total: 8448 + 32768 + 8192 + 16896 + 1024 = 67328 B -> 2 blocks/CU

    const int t  = threadIdx.x;
    const int b  = blockIdx.y;
    const int n0 = blockIdx.x * NT;
    const int p  = t & 63;                  // point within tile (lane id)
    const int q  = t >> 6;                  // wave index 0..3 (wave-uniform)
    const int qu = __builtin_amdgcn_readfirstlane(q);  // force scalar for weight indexing
    const int n  = n0 + p;

    // ---------------- Phase 1a: bilinear gather, channels qu*8..qu*8+7 ----------------
    {
        float xc = xy[((size_t)b * NPT + n) * 2 + 0];
        float yc = xy[((size_t)b * NPT + n) * 2 + 1];
        float ix = ((xc + 1.f) * (float)IW - 1.f) * 0.5f;
        float iy = ((yc + 1.f) * (float)H  - 1.f) * 0.5f;
        float fx0 = floorf(ix), fy0 = floorf(iy);
        float wx1 = ix - fx0, wx0f = 1.f - wx1;
        float wy1 = iy - fy0, wy0f = 1.f - wy1;
        int x0 = (int)fx0, y0 = (int)fy0;
        int x1 = x0 + 1,  y1 = y0 + 1;
        bool vx0 = (x0 >= 0) && (x0 < IW), vx1 = (x1 >= 0) && (x1 < IW);
        bool vy0 = (y0 >= 0) && (y0 < H),  vy1 = (y1 >= 0) && (y1 < H);
        int cx0 = min(max(x0, 0), IW - 1), cx1 = min(max(x1, 0), IW - 1);
        int cy0 = min(max(y0, 0), H - 1),  cy1 = min(max(y1, 0), H - 1);
        float w00 = wx0f * wy0f * ((vx0 && vy0) ? 1.f : 0.f);
        float w01 = wx1  * wy0f * ((vx1 && vy0) ? 1.f : 0.f);
        float w10 = wx0f * wy1  * ((vx0 && vy1) ? 1.f : 0.f);
        float w11 = wx1  * wy1  * ((vx1 && vy1) ? 1.f : 0.f);
        int o00 = cy0 * IW + cx0, o01 = cy0 * IW + cx1;
        int o10 = cy1 * IW + cx0, o11 = cy1 * IW + cx1;
        const float* fm = img_map + (size_t)b * IC * H * IW + (size_t)(qu * 8) * (H * IW);
        #pragma unroll
        for (int cc = 0; cc < 8; ++cc) {
            const float* f = fm + (size_t)cc * (H * IW);
            s_if[p][qu * 8 + cc] = w00 * f[o00] + w01 * f[o01] + w10 * f[o10] + w11 * f[o11];
        }
    }
    __syncthreads();

    // own point's img_feas into registers
    float fre[IC];
    #pragma unroll
    for (int c = 0; c < IC; ++c) fre[c] = s_if[p][c];

    // ---------------- Phase 1b-i: ri+rp for r = qu*8..qu*8+7, attention partial ------
    float racc[8];
    #pragma unroll
    for (int i = 0; i < 8; ++i) racc[i] = bf1[qu * 8 + i] + bf2[qu * 8 + i];
    {
        const float* pfb = point_feas + (size_t)b * PC * NPT + n;
        #pragma unroll 4
        for (int c = 0; c < PC; ++c) {
            float pf = pfb[(size_t)c * NPT];               // coalesced over lanes
            #pragma unroll
            for (int i = 0; i < 8; ++i)
                racc[i] += Wf2[(qu * 8 + i) * PC + c] * pf; // scalar (wave-uniform)
        }
    }
    #pragma unroll
    for (int c = 0; c < IC; ++c) {
        #pragma unroll
        for (int i = 0; i < 8; ++i)
            racc[i] += Wf1[(qu * 8 + i) * IC + c] * fre[c];
    }
    {
        float apart = 0.f;
        #pragma unroll
        for (int i = 0; i < 8; ++i) apart += Wf3[qu * 8 + i] * fast_tanh(racc[i]);
        s_attp[q][p] = apart;
    }
    __syncthreads();

    // ---------------- Phase 1b-ii: gated img_new, outputs o = qu*32..qu*32+31 --------
    {
        float att = fast_sigmoid(s_attp[0][p] + s_attp[1][p] + s_attp[2][p] + s_attp[3][p]
                                 + bf3[0]);
        #pragma unroll
        for (int oo = 0; oo < 32; ++oo) {
            int o = qu * 32 + oo;
            float acc = 0.f;
            #pragma unroll
            for (int c = 0; c < IC; ++c) acc += Wia[o * IC + c] * fre[c];
            float sc  = g1[o] * rsqrtf(v1[o] + EPS);
            float val = (acc + b_ia[o] - m1[o]) * sc + bt1[o];
            s_Ximg[o][p] = fmaxf(val, 0.f) * att;
        }
    }
    // (sync happens inside the first GEMM chunk before s_Ximg is ever read)

    // ---------------- Phase 2: out[o][n] = relu(bn2(Wfuse @ X)), tile 128x64 ---------
    const int tn  = t & 15;        // n-group 0..15 (full range inside each wave)
    const int to  = t >> 4;        // o-group 0..15 (wave-uniform-ish: 4 values/wave)
    const int oo0 = to * 8, nn0 = tn * 4;
    float acc[8][4];
    #pragma unroll
    for (int i = 0; i < 8; ++i)
        #pragma unroll
        for (int k = 0; k < 4; ++k) acc[i][k] = 0.f;

    for (int chk = 0; chk < 8; ++chk) {
        const int cb = chk * 32;
        // stage W_fuse^T chunk (coalesced read, transposed write, pad-4 LDS)
        #pragma unroll
        for (int j = 0; j < 16; ++j) {
            int idx = t + j * BDIM;
            int c = idx & 31, o = idx >> 5;
            s_Wt[c][o] = Wfuse[o * 256 + cb + c];
        }
        if (cb < PC) {
            // stage point_feas chunk (coalesced: lanes contiguous in n)
            #pragma unroll
            for (int j = 0; j < 8; ++j) {
                int idx = t + j * BDIM;
                int c = idx >> 6, pp = idx & 63;
                s_Xpf[c][pp] = point_feas[((size_t)b * PC + cb + c) * NPT + n0 + pp];
            }
        }
        __syncthreads();

        const float* Xb = (cb < PC) ? &s_Xpf[0][0] : &s_Ximg[cb - PC][0];  // both stride NT
        #pragma unroll 4
        for (int c = 0; c < 32; ++c) {
            float4 xv = *(const float4*)(Xb + c * NT + nn0);
            float4 wa = *(const float4*)(&s_Wt[c][oo0]);
            float4 wb = *(const float4*)(&s_Wt[c][oo0 + 4]);
            float wv[8] = {wa.x, wa.y, wa.z, wa.w, wb.x, wb.y, wb.z, wb.w};
            float xr[4] = {xv.x, xv.y, xv.z, xv.w};
            #pragma unroll
            for (int i = 0; i < 8; ++i)
                #pragma unroll
                for (int k = 0; k < 4; ++k)
                    acc[i][k] += wv[i] * xr[k];
        }
        __syncthreads();
    }

    // epilogue: fold bn2 + relu, float4 stores (16B aligned: n0%64==0, nn0%4==0)
    #pragma unroll
    for (int i = 0; i < 8; ++i) {
        int o = oo0 + i;
        float sc = g2[o] * rsqrtf(v2[o] + EPS);
        float bs = (b_fuse[o] - m2[o]) * sc + bt2[o];
        float4 r;
        r.x = fmaxf(acc[i][0] * sc + bs, 0.f);
        r.y = fmaxf(acc[i][1] * sc + bs, 0.f);
        r.z = fmaxf(acc[i][2] * sc + bs, 0.f);
        r.w = fmaxf(acc[i][3] * sc + bs, 0.f);
        *(float4*)(out + ((size_t)b * OUTC + o) * NPT + n0 + nn0) = r;
    }
}

extern "C" void kernel_launch(void* const* d_in, const int* in_sizes, int n_in,
                              void* d_out, int out_size, void* d_ws, size_t ws_size,
                              hipStream_t stream) {
    const float* img_map    = (const float*)d_in[0];
    const float* xy         = (const float*)d_in[1];
    const float* point_feas = (const float*)d_in[2];
    const float* Wia        = (const float*)d_in[3];
    const float* b_ia       = (const float*)d_in[4];
    const float* g1         = (const float*)d_in[5];
    const float* bt1        = (const float*)d_in[6];
    const float* m1         = (const float*)d_in[7];
    const float* v1         = (const float*)d_in[8];
    const float* Wf1        = (const float*)d_in[9];
    const float* bf1        = (const float*)d_in[10];
    const float* Wf2        = (const float*)d_in[11];
    const float* bf2        = (const float*)d_in[12];
    const float* Wf3        = (const float*)d_in[13];
    const float* bf3        = (const float*)d_in[14];
    const float* Wfuse      = (const float*)d_in[15];
    const float* b_fuse     = (const float*)d_in[16];
    const float* g2         = (const float*)d_in[17];
    const float* bt2        = (const float*)d_in[18];
    const float* m2         = (const float*)d_in[19];
    const float* v2         = (const float*)d_in[20];
    float* out = (float*)d_out;

    dim3 grid(NPT / NT, B);   // 32 x 64 = 2048 blocks
    rcnn_fused<<<grid, BDIM, 0, stream>>>(
        img_map, xy, point_feas, Wia, b_ia, g1, bt1, m1, v1,
        Wf1, bf1, Wf2, bf2, Wf3, bf3, Wfuse, b_fuse, g2, bt2, m2, v2, out);
}

// Round 2
// 567.922 us; speedup vs baseline: 1.1987x; 1.1987x over previous
//
#include <hip/hip_runtime.h>
#include <math.h>

typedef __attribute__((ext_vector_type(8))) short short8;
typedef __attribute__((ext_vector_type(4))) float floatx4;

constexpr int B    = 64;
constexpr int IC   = 32;
constexpr int PC   = 128;
constexpr int OUTC = 128;
constexpr int H    = 96;
constexpr int IW   = 320;
constexpr int NPT  = 2048;
constexpr float EPS = 1e-5f;

constexpr int BDIM = 256;
constexpr int NT   = 64;    // points per block

// fp32 -> bf16 round-to-nearest-even
__device__ __forceinline__ unsigned f2bf(float x) {
    unsigned u = __builtin_bit_cast(unsigned, x);
    u += 0x7FFFu + ((u >> 16) & 1u);
    return u >> 16;
}
__device__ __forceinline__ float fast_tanh(float v) {
    float e = __expf(2.f * v);
    return 1.f - 2.f / (e + 1.f);
}
__device__ __forceinline__ float fast_sigmoid(float v) {
    return 1.f / (1.f + __expf(-v));
}

__global__ __launch_bounds__(BDIM, 4) void rcnn_fused(
    const float* __restrict__ img_map, const float* __restrict__ xy,
    const float* __restrict__ point_feas,
    const float* __restrict__ Wia, const float* __restrict__ b_ia,
    const float* __restrict__ g1, const float* __restrict__ bt1,
    const float* __restrict__ m1, const float* __restrict__ v1,
    const float* __restrict__ Wf1, const float* __restrict__ bf1,
    const float* __restrict__ Wf2, const float* __restrict__ bf2,
    const float* __restrict__ Wf3, const float* __restrict__ bf3,
    const float* __restrict__ Wfuse, const float* __restrict__ b_fuse,
    const float* __restrict__ g2, const float* __restrict__ bt2,
    const float* __restrict__ m2, const float* __restrict__ v2,
    float* __restrict__ out)
{
    // persistent: img_new as bf16, [point n][img-channel k], K-contiguous for B-frags
    __shared__ __align__(16) short s_Ximg[NT][136];   // 17408 B (stride 272B = 17*16)
    // overlay: phase-1 {s_if, s_attp} aliases phase-2 {s_Wc, s_Xpf}
    __shared__ __align__(16) char s_ovl[15360];
    __shared__ float s_sc[OUTC], s_bs[OUTC];          // folded bn2 scale/bias
    // total LDS = 17408 + 15360 + 1024 = 33792 B -> 4 blocks/CU

    short (*s_Wc)[40]  = (short(*)[40])s_ovl;            // [128][40] bf16, 10240 B
    short (*s_Xpf)[40] = (short(*)[40])(s_ovl + 10240);  // [64][40]  bf16, 5120 B
    float (*s_if)[33]  = (float(*)[33])s_ovl;            // [64][33]  fp32, 8448 B
    float (*s_attp)[NT]= (float(*)[NT])(s_ovl + 8448);   // [4][64]   fp32, 1024 B

    const int t    = threadIdx.x;
    const int bid  = blockIdx.x;
    // XCD-aware swizzle: XCD x (= bid%8) processes batches x*8..x*8+7 in sequence,
    // so the per-batch img slice (3.9 MB) + pf slice (1 MB) stay L2-resident.
    const int xcd  = bid & 7;
    const int rr   = bid >> 3;
    const int b    = (xcd << 3) | (rr >> 5);
    const int n0   = (rr & 31) * NT;
    const int lane = t & 63;
    const int w    = t >> 6;
    const int wq   = __builtin_amdgcn_readfirstlane(w);
    const int n    = n0 + lane;

    // ---- phase 0: fold bn2 into scale/bias ----
    if (t < OUTC) {
        float sc = g2[t] * rsqrtf(v2[t] + EPS);
        s_sc[t] = sc;
        s_bs[t] = (b_fuse[t] - m2[t]) * sc + bt2[t];
    }

    // ---- phase 1a: bilinear gather, wave wq handles channels wq*8..wq*8+7 ----
    {
        float xc = xy[((size_t)b * NPT + n) * 2 + 0];
        float yc = xy[((size_t)b * NPT + n) * 2 + 1];
        float ix = ((xc + 1.f) * (float)IW - 1.f) * 0.5f;
        float iy = ((yc + 1.f) * (float)H  - 1.f) * 0.5f;
        float fx0 = floorf(ix), fy0 = floorf(iy);
        float wx1 = ix - fx0, wx0f = 1.f - wx1;
        float wy1 = iy - fy0, wy0f = 1.f - wy1;
        int x0 = (int)fx0, y0 = (int)fy0;
        int x1 = x0 + 1,  y1 = y0 + 1;
        bool vx0 = (x0 >= 0) && (x0 < IW), vx1 = (x1 >= 0) && (x1 < IW);
        bool vy0 = (y0 >= 0) && (y0 < H),  vy1 = (y1 >= 0) && (y1 < H);
        int cx0 = min(max(x0, 0), IW - 1), cx1 = min(max(x1, 0), IW - 1);
        int cy0 = min(max(y0, 0), H - 1),  cy1 = min(max(y1, 0), H - 1);
        float w00 = wx0f * wy0f * ((vx0 && vy0) ? 1.f : 0.f);
        float w01 = wx1  * wy0f * ((vx1 && vy0) ? 1.f : 0.f);
        float w10 = wx0f * wy1  * ((vx0 && vy1) ? 1.f : 0.f);
        float w11 = wx1  * wy1  * ((vx1 && vy1) ? 1.f : 0.f);
        int o00 = cy0 * IW + cx0, o01 = cy0 * IW + cx1;
        int o10 = cy1 * IW + cx0, o11 = cy1 * IW + cx1;
        const float* fm = img_map + (size_t)b * IC * H * IW + (size_t)(wq * 8) * (H * IW);
        #pragma unroll
        for (int cc = 0; cc < 8; ++cc) {
            const float* f = fm + (size_t)cc * (H * IW);
            s_if[lane][wq * 8 + cc] = w00 * f[o00] + w01 * f[o01] + w10 * f[o10] + w11 * f[o11];
        }
    }
    __syncthreads();

    float fre[IC];
    #pragma unroll
    for (int c = 0; c < IC; ++c) fre[c] = s_if[lane][c];

    // ---- phase 1b-i: ri+rp rows wq*8..wq*8+7, attention partial ----
    {
        float racc[8];
        #pragma unroll
        for (int i = 0; i < 8; ++i) racc[i] = bf1[wq * 8 + i] + bf2[wq * 8 + i];
        const float* pfb = point_feas + (size_t)b * PC * NPT + n;
        #pragma unroll 4
        for (int c = 0; c < PC; ++c) {
            float pf = pfb[(size_t)c * NPT];                // coalesced; L1-hit for waves 1..3
            #pragma unroll
            for (int i = 0; i < 8; ++i)
                racc[i] += Wf2[(wq * 8 + i) * PC + c] * pf;  // scalar weight loads
        }
        #pragma unroll
        for (int c = 0; c < IC; ++c) {
            #pragma unroll
            for (int i = 0; i < 8; ++i)
                racc[i] += Wf1[(wq * 8 + i) * IC + c] * fre[c];
        }
        float apart = 0.f;
        #pragma unroll
        for (int i = 0; i < 8; ++i) apart += Wf3[wq * 8 + i] * fast_tanh(racc[i]);
        s_attp[w][lane] = apart;
    }
    __syncthreads();

    // ---- phase 1b-ii: gated img_new -> bf16 into s_Ximg[point][o] ----
    {
        float att = fast_sigmoid(s_attp[0][lane] + s_attp[1][lane] + s_attp[2][lane]
                                 + s_attp[3][lane] + bf3[0]);
        #pragma unroll
        for (int jj = 0; jj < 4; ++jj) {
            short8 v;
            #pragma unroll
            for (int e = 0; e < 8; ++e) {
                int o = wq * 32 + jj * 8 + e;
                float acc = 0.f;
                #pragma unroll
                for (int c = 0; c < IC; ++c) acc += Wia[o * IC + c] * fre[c];
                float sc  = g1[o] * rsqrtf(v1[o] + EPS);
                float val = (acc + b_ia[o] - m1[o]) * sc + bt1[o];
                val = fmaxf(val, 0.f) * att;
                v[e] = (short)f2bf(val);
            }
            *(short8*)&s_Ximg[lane][wq * 32 + jj * 8] = v;
        }
    }
    __syncthreads();   // protects s_if/s_attp before overlay reuse + s_Ximg before reads

    // ---- phase 2: MFMA GEMM out[128][64] = Wfuse(128x256) @ X(256x64) ----
    const int row16 = lane & 15;
    const int quad  = lane >> 4;
    floatx4 acc[2][4];
    #pragma unroll
    for (int mt = 0; mt < 2; ++mt)
        #pragma unroll
        for (int nt = 0; nt < 4; ++nt) acc[mt][nt] = (floatx4){0.f, 0.f, 0.f, 0.f};

    for (int chk = 0; chk < 8; ++chk) {
        const int k0 = chk * 32;
        // stage W chunk: Wfuse[0..127][k0..k0+31] fp32 -> bf16 s_Wc[o][c]
        #pragma unroll
        for (int j = 0; j < 8; ++j) {
            int idx = j * 256 + t;
            int c2 = (idx & 15) * 2, o = idx >> 4;
            float2 wv = *(const float2*)&Wfuse[o * 256 + k0 + c2];
            *(unsigned*)&s_Wc[o][c2] = f2bf(wv.x) | (f2bf(wv.y) << 16);
        }
        if (chk < 4) {
            // stage pf chunk transposed: pf[b][k0+c][n0+n] -> s_Xpf[n][c] bf16
            #pragma unroll
            for (int j = 0; j < 4; ++j) {
                int idx = j * 256 + t;
                int n2 = (idx & 31) * 2, c = idx >> 5;
                float2 pv = *(const float2*)&point_feas[((size_t)b * PC + k0 + c) * NPT + n0 + n2];
                s_Xpf[n2][c]     = (short)f2bf(pv.x);
                s_Xpf[n2 + 1][c] = (short)f2bf(pv.y);
            }
        }
        __syncthreads();

        short8 afr[2], bfr[4];
        #pragma unroll
        for (int mt = 0; mt < 2; ++mt)
            afr[mt] = *(const short8*)&s_Wc[wq * 32 + mt * 16 + row16][quad * 8];
        #pragma unroll
        for (int nt = 0; nt < 4; ++nt) {
            const short* src = (chk < 4) ? &s_Xpf[nt * 16 + row16][quad * 8]
                                         : &s_Ximg[nt * 16 + row16][(chk - 4) * 32 + quad * 8];
            bfr[nt] = *(const short8*)src;
        }
        #pragma unroll
        for (int mt = 0; mt < 2; ++mt)
            #pragma unroll
            for (int nt = 0; nt < 4; ++nt)
                acc[mt][nt] = __builtin_amdgcn_mfma_f32_16x16x32_bf16(
                                  afr[mt], bfr[nt], acc[mt][nt], 0, 0, 0);
        if (chk != 7) __syncthreads();
    }

    // ---- epilogue: bn2 + relu, C/D layout col=lane&15, row=quad*4+reg ----
    #pragma unroll
    for (int mt = 0; mt < 2; ++mt) {
        #pragma unroll
        for (int nt = 0; nt < 4; ++nt) {
            #pragma unroll
            for (int r2 = 0; r2 < 4; ++r2) {
                int o = wq * 32 + mt * 16 + quad * 4 + r2;
                float val = fmaxf(acc[mt][nt][r2] * s_sc[o] + s_bs[o], 0.f);
                out[((size_t)b * OUTC + o) * NPT + n0 + nt * 16 + row16] = val;
            }
        }
    }
}

extern "C" void kernel_launch(void* const* d_in, const int* in_sizes, int n_in,
                              void* d_out, int out_size, void* d_ws, size_t ws_size,
                              hipStream_t stream) {
    const float* img_map    = (const float*)d_in[0];
    const float* xy         = (const float*)d_in[1];
    const float* point_feas = (const float*)d_in[2];
    const float* Wia        = (const float*)d_in[3];
    const float* b_ia       = (const float*)d_in[4];
    const float* g1         = (const float*)d_in[5];
    const float* bt1        = (const float*)d_in[6];
    const float* m1         = (const float*)d_in[7];
    const float* v1         = (const float*)d_in[8];
    const float* Wf1        = (const float*)d_in[9];
    const float* bf1        = (const float*)d_in[10];
    const float* Wf2        = (const float*)d_in[11];
    const float* bf2        = (const float*)d_in[12];
    const float* Wf3        = (const float*)d_in[13];
    const float* bf3        = (const float*)d_in[14];
    const float* Wfuse      = (const float*)d_in[15];
    const float* b_fuse     = (const float*)d_in[16];
    const float* g2         = (const float*)d_in[17];
    const float* bt2        = (const float*)d_in[18];
    const float* m2         = (const float*)d_in[19];
    const float* v2         = (const float*)d_in[20];
    float* out = (float*)d_out;

    rcnn_fused<<<dim3(2048), BDIM, 0, stream>>>(
        img_map, xy, point_feas, Wia, b_ia, g1, bt1, m1, v1,
        Wf1, bf1, Wf2, bf2, Wf3, bf3, Wfuse, b_fuse, g2, bt2, m2, v2, out);
}

// Round 3
// 547.416 us; speedup vs baseline: 1.2436x; 1.0375x over previous
//
#include <hip/hip_runtime.h>
#include <math.h>

typedef __attribute__((ext_vector_type(8))) short short8;
typedef __attribute__((ext_vector_type(4))) float floatx4;

constexpr int B    = 64;
constexpr int IC   = 32;
constexpr int PC   = 128;
constexpr int OUTC = 128;
constexpr int H    = 96;
constexpr int IW   = 320;
constexpr int NPT  = 2048;
constexpr float EPS = 1e-5f;

__device__ __forceinline__ unsigned f2bf(float x) {
    unsigned u = __builtin_bit_cast(unsigned, x);
    u += 0x7FFFu + ((u >> 16) & 1u);
    return u >> 16;
}
__device__ __forceinline__ float fast_tanh(float v) {
    float e = __expf(2.f * v);
    return 1.f - 2.f / (e + 1.f);
}
__device__ __forceinline__ float fast_sigmoid(float v) {
    return 1.f / (1.f + __expf(-v));
}

// =====================================================================
// Kernel 1: gather + attention + conv1 -> X bf16 [b][n][k] (k=0..127 pf,
// k=128..255 img_new), plus one-time Wfuse->bf16 conversion (blocks 0..7).
// =====================================================================
__global__ __launch_bounds__(256, 4) void k1_prep(
    const float* __restrict__ img_map, const float* __restrict__ xy,
    const float* __restrict__ point_feas,
    const float* __restrict__ Wia, const float* __restrict__ b_ia,
    const float* __restrict__ g1, const float* __restrict__ bt1,
    const float* __restrict__ m1, const float* __restrict__ v1,
    const float* __restrict__ Wf1, const float* __restrict__ bf1,
    const float* __restrict__ Wf2, const float* __restrict__ bf2,
    const float* __restrict__ Wf3, const float* __restrict__ bf3,
    const float* __restrict__ Wfuse,
    short* __restrict__ Xg, short* __restrict__ Wb)
{
    __shared__ float s_if[64][33];
    __shared__ float s_attp[4][64];
    __shared__ short s_Xpf[64 * 128];   // XOR-swizzled [point][k-oct], no pad

    const int t = threadIdx.x, bid = blockIdx.x;
    const int xcd = bid & 7, rr = bid >> 3;
    const int b  = (xcd << 3) | (rr >> 5);
    const int n0 = (rr & 31) * 64;
    const int lane = t & 63, w = t >> 6;
    const int wq = __builtin_amdgcn_readfirstlane(w);
    const int n = n0 + lane;

    // one-time W conversion (race-free: disjoint ranges, only k2 reads it)
    if (bid < 8) {
        #pragma unroll
        for (int j = 0; j < 16; ++j) {
            int idx = bid * 4096 + j * 256 + t;
            Wb[idx] = (short)f2bf(Wfuse[idx]);
        }
    }

    // ---- bilinear gather: wave wq -> channels wq*8..wq*8+7 ----
    {
        float xc = xy[((size_t)b * NPT + n) * 2 + 0];
        float yc = xy[((size_t)b * NPT + n) * 2 + 1];
        float ix = ((xc + 1.f) * (float)IW - 1.f) * 0.5f;
        float iy = ((yc + 1.f) * (float)H  - 1.f) * 0.5f;
        float fx0 = floorf(ix), fy0 = floorf(iy);
        float wx1 = ix - fx0, wx0f = 1.f - wx1;
        float wy1 = iy - fy0, wy0f = 1.f - wy1;
        int x0 = (int)fx0, y0 = (int)fy0;
        int x1 = x0 + 1,  y1 = y0 + 1;
        bool vx0 = (x0 >= 0) && (x0 < IW), vx1 = (x1 >= 0) && (x1 < IW);
        bool vy0 = (y0 >= 0) && (y0 < H),  vy1 = (y1 >= 0) && (y1 < H);
        int cx0 = min(max(x0, 0), IW - 1), cx1 = min(max(x1, 0), IW - 1);
        int cy0 = min(max(y0, 0), H - 1),  cy1 = min(max(y1, 0), H - 1);
        float w00 = wx0f * wy0f * ((vx0 && vy0) ? 1.f : 0.f);
        float w01 = wx1  * wy0f * ((vx1 && vy0) ? 1.f : 0.f);
        float w10 = wx0f * wy1  * ((vx0 && vy1) ? 1.f : 0.f);
        float w11 = wx1  * wy1  * ((vx1 && vy1) ? 1.f : 0.f);
        int o00 = cy0 * IW + cx0, o01 = cy0 * IW + cx1;
        int o10 = cy1 * IW + cx0, o11 = cy1 * IW + cx1;
        const float* fm = img_map + (size_t)b * IC * H * IW + (size_t)(wq * 8) * (H * IW);
        #pragma unroll
        for (int cc = 0; cc < 8; ++cc) {
            const float* f = fm + (size_t)cc * (H * IW);
            s_if[lane][wq * 8 + cc] = w00 * f[o00] + w01 * f[o01] + w10 * f[o10] + w11 * f[o11];
        }
    }
    __syncthreads();

    float fre[IC];
    #pragma unroll
    for (int c = 0; c < IC; ++c) fre[c] = s_if[lane][c];

    // ---- attention: rp (128ch) + ri (32ch), rows wq*8..wq*8+7 ----
    const float* pfb = point_feas + (size_t)b * PC * NPT + n;
    {
        float racc[8];
        #pragma unroll
        for (int i = 0; i < 8; ++i) racc[i] = bf1[wq * 8 + i] + bf2[wq * 8 + i];
        #pragma unroll 4
        for (int c = 0; c < PC; ++c) {
            float pf = pfb[(size_t)c * NPT];
            #pragma unroll
            for (int i = 0; i < 8; ++i)
                racc[i] += Wf2[(wq * 8 + i) * PC + c] * pf;
        }
        #pragma unroll
        for (int c = 0; c < IC; ++c) {
            #pragma unroll
            for (int i = 0; i < 8; ++i)
                racc[i] += Wf1[(wq * 8 + i) * IC + c] * fre[c];
        }
        float apart = 0.f;
        #pragma unroll
        for (int i = 0; i < 8; ++i) apart += Wf3[wq * 8 + i] * fast_tanh(racc[i]);
        s_attp[w][lane] = apart;
    }

    // ---- pf -> bf16 into XOR-swizzled LDS (wave wq: k = wq*32..wq*32+31) ----
    // slot(p, k) = p*128 + ((koct ^ (p&15))<<3) + (k&7) : conflict-free writes/reads
    #pragma unroll
    for (int cc = 0; cc < 16; ++cc) {
        int k0 = wq * 32 + cc * 2;
        float a0 = pfb[(size_t)k0 * NPT];          // L1-hot (read in rp loop)
        float a1 = pfb[(size_t)(k0 + 1) * NPT];
        unsigned pack = f2bf(a0) | (f2bf(a1) << 16);
        int koct = k0 >> 3;
        int sidx = lane * 128 + ((koct ^ (lane & 15)) << 3) + (k0 & 7);
        *(unsigned*)&s_Xpf[sidx] = pack;
    }
    __syncthreads();

    // ---- att + conv1 -> img_new bf16, direct global short8 stores ----
    {
        float att = fast_sigmoid(s_attp[0][lane] + s_attp[1][lane] + s_attp[2][lane]
                                 + s_attp[3][lane] + bf3[0]);
        #pragma unroll
        for (int jj = 0; jj < 4; ++jj) {
            short8 v;
            #pragma unroll
            for (int e = 0; e < 8; ++e) {
                int o = wq * 32 + jj * 8 + e;
                float acc = 0.f;
                #pragma unroll
                for (int c = 0; c < IC; ++c) acc += Wia[o * IC + c] * fre[c];
                float sc  = g1[o] * rsqrtf(v1[o] + EPS);
                float val = (acc + b_ia[o] - m1[o]) * sc + bt1[o];
                val = fmaxf(val, 0.f) * att;
                v[e] = (short)f2bf(val);
            }
            *(short8*)(Xg + ((size_t)(b * NPT + n)) * 256 + 128 + wq * 32 + jj * 8) = v;
        }
    }

    // ---- pf readout: LDS -> global X[b][n][k], fully vectorized ----
    #pragma unroll
    for (int j = 0; j < 4; ++j) {
        int idx = j * 256 + t;
        int nn = idx >> 4, koct = idx & 15;
        short8 v = *(const short8*)&s_Xpf[nn * 128 + ((koct ^ (nn & 15)) << 3)];
        *(short8*)(Xg + ((size_t)(b * NPT + n0 + nn)) * 256 + koct * 8) = v;
    }
}

// =====================================================================
// Kernel 2: out[b][128][2048] = relu(bn2(Wfuse @ X)), bf16 MFMA GEMM
// tile 128x128, K=256 in 4 chunks of 64.
// =====================================================================
__global__ __launch_bounds__(256, 4) void k2_gemm(
    const short* __restrict__ Xg, const short* __restrict__ Wb,
    const float* __restrict__ b_fuse, const float* __restrict__ g2,
    const float* __restrict__ bt2, const float* __restrict__ m2,
    const float* __restrict__ v2, float* __restrict__ out)
{
    __shared__ __align__(16) short sA[128][72];   // [o][k], 144B rows (9*16B)
    __shared__ __align__(16) short sB[128][72];   // [n][k]
    __shared__ float s_sc[OUTC], s_bs[OUTC];

    const int t = threadIdx.x;
    const int b  = blockIdx.x >> 4;
    const int n0 = (blockIdx.x & 15) * 128;
    const int lane = t & 63, w = t >> 6;
    const int wq = __builtin_amdgcn_readfirstlane(w);
    const int mh = (wq & 1) * 64, nh = (wq >> 1) * 64;
    const int r16 = lane & 15, quad = lane >> 4;

    if (t < OUTC) {
        float sc = g2[t] * rsqrtf(v2[t] + EPS);
        s_sc[t] = sc;
        s_bs[t] = (b_fuse[t] - m2[t]) * sc + bt2[t];
    }

    floatx4 acc[4][4];
    #pragma unroll
    for (int mt = 0; mt < 4; ++mt)
        #pragma unroll
        for (int nt = 0; nt < 4; ++nt) acc[mt][nt] = (floatx4){0.f, 0.f, 0.f, 0.f};

    const short* Xrow = Xg + (size_t)(b * NPT + n0) * 256;

    for (int kk = 0; kk < 4; ++kk) {
        const int kb = kk * 64;
        #pragma unroll
        for (int j = 0; j < 4; ++j) {
            int idx = j * 256 + t;             // 0..1023
            int m = idx >> 3, ko = idx & 7;    // 8 lanes = 128B contiguous
            *(short8*)&sA[m][ko * 8] = *(const short8*)(Wb + m * 256 + kb + ko * 8);
            *(short8*)&sB[m][ko * 8] = *(const short8*)(Xrow + (size_t)m * 256 + kb + ko * 8);
        }
        __syncthreads();

        #pragma unroll
        for (int kq = 0; kq < 2; ++kq) {
            short8 af[4], bf[4];
            #pragma unroll
            for (int mt = 0; mt < 4; ++mt)
                af[mt] = *(const short8*)&sA[mh + mt * 16 + r16][kq * 32 + quad * 8];
            #pragma unroll
            for (int nt = 0; nt < 4; ++nt)
                bf[nt] = *(const short8*)&sB[nh + nt * 16 + r16][kq * 32 + quad * 8];
            #pragma unroll
            for (int mt = 0; mt < 4; ++mt)
                #pragma unroll
                for (int nt = 0; nt < 4; ++nt)
                    acc[mt][nt] = __builtin_amdgcn_mfma_f32_16x16x32_bf16(
                                      af[mt], bf[nt], acc[mt][nt], 0, 0, 0);
        }
        if (kk != 3) __syncthreads();
    }

    // epilogue: C/D layout col=lane&15 (n), row=quad*4+reg (o)
    #pragma unroll
    for (int mt = 0; mt < 4; ++mt) {
        #pragma unroll
        for (int nt = 0; nt < 4; ++nt) {
            #pragma unroll
            for (int r2 = 0; r2 < 4; ++r2) {
                int o = mh + mt * 16 + quad * 4 + r2;
                int nc = n0 + nh + nt * 16 + r16;
                float val = fmaxf(acc[mt][nt][r2] * s_sc[o] + s_bs[o], 0.f);
                out[((size_t)b * OUTC + o) * NPT + nc] = val;
            }
        }
    }
}

// =====================================================================
// Fallback: R2 fused single-kernel (used only if ws_size is too small)
// =====================================================================
__global__ __launch_bounds__(256, 4) void rcnn_fused(
    const float* __restrict__ img_map, const float* __restrict__ xy,
    const float* __restrict__ point_feas,
    const float* __restrict__ Wia, const float* __restrict__ b_ia,
    const float* __restrict__ g1, const float* __restrict__ bt1,
    const float* __restrict__ m1, const float* __restrict__ v1,
    const float* __restrict__ Wf1, const float* __restrict__ bf1,
    const float* __restrict__ Wf2, const float* __restrict__ bf2,
    const float* __restrict__ Wf3, const float* __restrict__ bf3,
    const float* __restrict__ Wfuse, const float* __restrict__ b_fuse,
    const float* __restrict__ g2, const float* __restrict__ bt2,
    const float* __restrict__ m2, const float* __restrict__ v2,
    float* __restrict__ out)
{
    __shared__ __align__(16) short s_Ximg[64][136];
    __shared__ __align__(16) char s_ovl[15360];
    __shared__ float s_sc[OUTC], s_bs[OUTC];

    short (*s_Wc)[40]  = (short(*)[40])s_ovl;
    short (*s_Xpf)[40] = (short(*)[40])(s_ovl + 10240);
    float (*s_if)[33]  = (float(*)[33])s_ovl;
    float (*s_attp)[64]= (float(*)[64])(s_ovl + 8448);

    const int t = threadIdx.x, bid = blockIdx.x;
    const int xcd = bid & 7, rr = bid >> 3;
    const int b = (xcd << 3) | (rr >> 5);
    const int n0 = (rr & 31) * 64;
    const int lane = t & 63, w = t >> 6;
    const int wq = __builtin_amdgcn_readfirstlane(w);
    const int n = n0 + lane;

    if (t < OUTC) {
        float sc = g2[t] * rsqrtf(v2[t] + EPS);
        s_sc[t] = sc;
        s_bs[t] = (b_fuse[t] - m2[t]) * sc + bt2[t];
    }
    {
        float xc = xy[((size_t)b * NPT + n) * 2 + 0];
        float yc = xy[((size_t)b * NPT + n) * 2 + 1];
        float ix = ((xc + 1.f) * (float)IW - 1.f) * 0.5f;
        float iy = ((yc + 1.f) * (float)H  - 1.f) * 0.5f;
        float fx0 = floorf(ix), fy0 = floorf(iy);
        float wx1 = ix - fx0, wx0f = 1.f - wx1;
        float wy1 = iy - fy0, wy0f = 1.f - wy1;
        int x0 = (int)fx0, y0 = (int)fy0;
        int x1 = x0 + 1,  y1 = y0 + 1;
        bool vx0 = (x0 >= 0) && (x0 < IW), vx1 = (x1 >= 0) && (x1 < IW);
        bool vy0 = (y0 >= 0) && (y0 < H),  vy1 = (y1 >= 0) && (y1 < H);
        int cx0 = min(max(x0, 0), IW - 1), cx1 = min(max(x1, 0), IW - 1);
        int cy0 = min(max(y0, 0), H - 1),  cy1 = min(max(y1, 0), H - 1);
        float w00 = wx0f * wy0f * ((vx0 && vy0) ? 1.f : 0.f);
        float w01 = wx1  * wy0f * ((vx1 && vy0) ? 1.f : 0.f);
        float w10 = wx0f * wy1  * ((vx0 && vy1) ? 1.f : 0.f);
        float w11 = wx1  * wy1  * ((vx1 && vy1) ? 1.f : 0.f);
        int o00 = cy0 * IW + cx0, o01 = cy0 * IW + cx1;
        int o10 = cy1 * IW + cx0, o11 = cy1 * IW + cx1;
        const float* fm = img_map + (size_t)b * IC * H * IW + (size_t)(wq * 8) * (H * IW);
        #pragma unroll
        for (int cc = 0; cc < 8; ++cc) {
            const float* f = fm + (size_t)cc * (H * IW);
            s_if[lane][wq * 8 + cc] = w00 * f[o00] + w01 * f[o01] + w10 * f[o10] + w11 * f[o11];
        }
    }
    __syncthreads();
    float fre[IC];
    #pragma unroll
    for (int c = 0; c < IC; ++c) fre[c] = s_if[lane][c];
    {
        float racc[8];
        #pragma unroll
        for (int i = 0; i < 8; ++i) racc[i] = bf1[wq * 8 + i] + bf2[wq * 8 + i];
        const float* pfb = point_feas + (size_t)b * PC * NPT + n;
        #pragma unroll 4
        for (int c = 0; c < PC; ++c) {
            float pf = pfb[(size_t)c * NPT];
            #pragma unroll
            for (int i = 0; i < 8; ++i)
                racc[i] += Wf2[(wq * 8 + i) * PC + c] * pf;
        }
        #pragma unroll
        for (int c = 0; c < IC; ++c) {
            #pragma unroll
            for (int i = 0; i < 8; ++i)
                racc[i] += Wf1[(wq * 8 + i) * IC + c] * fre[c];
        }
        float apart = 0.f;
        #pragma unroll
        for (int i = 0; i < 8; ++i) apart += Wf3[wq * 8 + i] * fast_tanh(racc[i]);
        s_attp[w][lane] = apart;
    }
    __syncthreads();
    {
        float att = fast_sigmoid(s_attp[0][lane] + s_attp[1][lane] + s_attp[2][lane]
                                 + s_attp[3][lane] + bf3[0]);
        #pragma unroll
        for (int jj = 0; jj < 4; ++jj) {
            short8 v;
            #pragma unroll
            for (int e = 0; e < 8; ++e) {
                int o = wq * 32 + jj * 8 + e;
                float acc = 0.f;
                #pragma unroll
                for (int c = 0; c < IC; ++c) acc += Wia[o * IC + c] * fre[c];
                float sc  = g1[o] * rsqrtf(v1[o] + EPS);
                float val = (acc + b_ia[o] - m1[o]) * sc + bt1[o];
                val = fmaxf(val, 0.f) * att;
                v[e] = (short)f2bf(val);
            }
            *(short8*)&s_Ximg[lane][wq * 32 + jj * 8] = v;
        }
    }
    __syncthreads();

    const int row16 = lane & 15;
    const int quad  = lane >> 4;
    floatx4 acc[2][4];
    #pragma unroll
    for (int mt = 0; mt < 2; ++mt)
        #pragma unroll
        for (int nt = 0; nt < 4; ++nt) acc[mt][nt] = (floatx4){0.f, 0.f, 0.f, 0.f};

    for (int chk = 0; chk < 8; ++chk) {
        const int k0 = chk * 32;
        #pragma unroll
        for (int j = 0; j < 8; ++j) {
            int idx = j * 256 + t;
            int c2 = (idx & 15) * 2, o = idx >> 4;
            float2 wv = *(const float2*)&Wfuse[o * 256 + k0 + c2];
            *(unsigned*)&s_Wc[o][c2] = f2bf(wv.x) | (f2bf(wv.y) << 16);
        }
        if (chk < 4) {
            #pragma unroll
            for (int j = 0; j < 4; ++j) {
                int idx = j * 256 + t;
                int n2 = (idx & 31) * 2, c = idx >> 5;
                float2 pv = *(const float2*)&point_feas[((size_t)b * PC + k0 + c) * NPT + n0 + n2];
                s_Xpf[n2][c]     = (short)f2bf(pv.x);
                s_Xpf[n2 + 1][c] = (short)f2bf(pv.y);
            }
        }
        __syncthreads();

        short8 afr[2], bfr[4];
        #pragma unroll
        for (int mt = 0; mt < 2; ++mt)
            afr[mt] = *(const short8*)&s_Wc[wq * 32 + mt * 16 + row16][quad * 8];
        #pragma unroll
        for (int nt = 0; nt < 4; ++nt) {
            const short* src = (chk < 4) ? &s_Xpf[nt * 16 + row16][quad * 8]
                                         : &s_Ximg[nt * 16 + row16][(chk - 4) * 32 + quad * 8];
            bfr[nt] = *(const short8*)src;
        }
        #pragma unroll
        for (int mt = 0; mt < 2; ++mt)
            #pragma unroll
            for (int nt = 0; nt < 4; ++nt)
                acc[mt][nt] = __builtin_amdgcn_mfma_f32_16x16x32_bf16(
                                  afr[mt], bfr[nt], acc[mt][nt], 0, 0, 0);
        if (chk != 7) __syncthreads();
    }
    #pragma unroll
    for (int mt = 0; mt < 2; ++mt) {
        #pragma unroll
        for (int nt = 0; nt < 4; ++nt) {
            #pragma unroll
            for (int r2 = 0; r2 < 4; ++r2) {
                int o = wq * 32 + mt * 16 + quad * 4 + r2;
                float val = fmaxf(acc[mt][nt][r2] * s_sc[o] + s_bs[o], 0.f);
                out[((size_t)b * OUTC + o) * NPT + n0 + nt * 16 + row16] = val;
            }
        }
    }
}

extern "C" void kernel_launch(void* const* d_in, const int* in_sizes, int n_in,
                              void* d_out, int out_size, void* d_ws, size_t ws_size,
                              hipStream_t stream) {
    const float* img_map    = (const float*)d_in[0];
    const float* xy         = (const float*)d_in[1];
    const float* point_feas = (const float*)d_in[2];
    const float* Wia        = (const float*)d_in[3];
    const float* b_ia       = (const float*)d_in[4];
    const float* g1         = (const float*)d_in[5];
    const float* bt1        = (const float*)d_in[6];
    const float* m1         = (const float*)d_in[7];
    const float* v1         = (const float*)d_in[8];
    const float* Wf1        = (const float*)d_in[9];
    const float* bf1        = (const float*)d_in[10];
    const float* Wf2        = (const float*)d_in[11];
    const float* bf2        = (const float*)d_in[12];
    const float* Wf3        = (const float*)d_in[13];
    const float* bf3        = (const float*)d_in[14];
    const float* Wfuse      = (const float*)d_in[15];
    const float* b_fuse     = (const float*)d_in[16];
    const float* g2         = (const float*)d_in[17];
    const float* bt2        = (const float*)d_in[18];
    const float* m2         = (const float*)d_in[19];
    const float* v2         = (const float*)d_in[20];
    float* out = (float*)d_out;

    const size_t need = 65536 + (size_t)B * NPT * 256 * 2;  // Wb + X
    if (ws_size >= need) {
        short* Wb = (short*)d_ws;
        short* Xg = (short*)((char*)d_ws + 65536);
        k1_prep<<<dim3(2048), 256, 0, stream>>>(
            img_map, xy, point_feas, Wia, b_ia, g1, bt1, m1, v1,
            Wf1, bf1, Wf2, bf2, Wf3, bf3, Wfuse, Xg, Wb);
        k2_gemm<<<dim3(1024), 256, 0, stream>>>(
            Xg, Wb, b_fuse, g2, bt2, m2, v2, out);
    } else {
        rcnn_fused<<<dim3(2048), 256, 0, stream>>>(
            img_map, xy, point_feas, Wia, b_ia, g1, bt1, m1, v1,
            Wf1, bf1, Wf2, bf2, Wf3, bf3, Wfuse, b_fuse, g2, bt2, m2, v2, out);
    }
}